// Round 12
// baseline (472.567 us; speedup 1.0000x reference)
//
#include <hip/hip_runtime.h>
#include <hip/hip_bf16.h>
#include <math.h>

// Problem constants
#define NB   16      // batch
#define NIN  512
#define NN   2048
#define KN   28672   // K*N
#define KN2  14336   // KN/2
#define INVNONE 0x7fffffff
#define NC   64      // n-chunks for k3 (nper = 32)

// ---------------------------------------------------------------------------
// k1: partial GEMM i_in = inputs @ W, f64 accumulation, deterministic order.
// part[ks][b][n], ks in [0,16) covering k = ks*32 .. ks*32+31.
// grid (32 n-chunks, 16 ks), block = 64 threads (one wave, 64 n's).
// Also clears zmask (ks==0 blocks) and inits inv[] (all blocks, 1 elem/thread).
__global__ __launch_bounds__(64) void k1_gemm(const float* __restrict__ inputs,
                                              const float* __restrict__ W,
                                              double* __restrict__ part,
                                              unsigned int* __restrict__ zmask,
                                              int* __restrict__ inv) {
    const int n  = blockIdx.x * 64 + threadIdx.x;
    const int ks = blockIdx.y;
    if (ks == 0) zmask[n] = 0u;                 // fused clear
    int fid = (ks * 32 + blockIdx.x) * 64 + threadIdx.x;   // [0, 32768)
    if (fid < KN) inv[fid] = INVNONE;           // fused inv init
    const int k0 = ks * 32;
    double acc[16];
    #pragma unroll
    for (int b = 0; b < 16; ++b) acc[b] = 0.0;
    #pragma unroll 8
    for (int kk = 0; kk < 32; ++kk) {           // 8 W-loads batched in flight
        double w = (double)W[(size_t)(k0 + kk) * NN + n];   // coalesced 256B/wave
        #pragma unroll
        for (int b = 0; b < 16; ++b)                        // uniform scalar loads
            acc[b] += w * (double)inputs[b * NIN + k0 + kk];
    }
    #pragma unroll
    for (int b = 0; b < 16; ++b)
        part[(size_t)(ks * 16 + b) * NN + n] = acc[b];
}

// ---------------------------------------------------------------------------
// k2: deterministic reduce of 16 partials + LIF update. Writes new_z, new_v,
// per-neuron 16-bit spike mask (atomicOr = order-independent), and fused
// kM: inv[col] = min slot with ridx[slot]==col (atomicMin -> deterministic).
__global__ __launch_bounds__(256) void k2_point(const double* __restrict__ part,
                                                const float* __restrict__ old_v,
                                                const float* __restrict__ old_spike,
                                                const int* __restrict__ tt_p,
                                                const int* __restrict__ ridx,
                                                float* __restrict__ out,      // z @0, v @32768
                                                unsigned int* __restrict__ zmask,
                                                int* __restrict__ inv) {
    int gid = blockIdx.x * 256 + threadIdx.x;   // [0, 32768)
    if (gid < NN) atomicMin(&inv[ridx[gid]], gid);   // fused kM
    int b = gid >> 11, n = gid & (NN - 1);
    double s = 0.0;
    #pragma unroll
    for (int ks = 0; ks < 16; ++ks)             // fixed order -> deterministic
        s += part[(size_t)(ks * 16 + b) * NN + n];
    double tt   = (double)tt_p[0];
    double bias = 0.5 * sin(2.0 * 3.14159265358979323846 * 4.0 * (0.001 * tt));
    double d    = 0.9512294245007140;           // exp(-1/20)
    double i_in = s + bias;
    double nv   = d * (double)old_v[gid] + (1.0 - d) * i_in
                  - 0.03 * (double)old_spike[gid];
    bool z = nv > 0.03;                          // v_scaled > 0  <=>  nv > THR
    out[gid]           = z ? 1.0f : 0.0f;
    out[32768 + gid]   = (float)nv;
    if (z) atomicOr(&zmask[n], 1u << b);
}

// ---------------------------------------------------------------------------
// k3: streamed masked row-sum of B via global_load_lds DMA pipeline.
// 1-wave blocks, NO barriers. Wave owns 64 float2 cols x 32 rows: issues 16
// DMA stages (2 rows / 1KB each) upfront, consumes in issue order with
// counted s_waitcnt vmcnt(15-r) (never drains to 0 until the end).
// In-flight bytes come from the DMA queue, not VGPRs: acc 32 + ~16 misc VGPR.
#define WAITV(N_) do {                                                      \
    asm volatile("s_waitcnt vmcnt(" #N_ ")" ::: "memory");                  \
    __builtin_amdgcn_sched_barrier(0);                                      \
} while (0)

#define STAGE(R_) do {                                                      \
    const char* s_ = gbase + (size_t)(2 * (R_)) * SB +                      \
        (t < 32 ? (size_t)t * 16 : SB + (size_t)(t - 32) * 16);             \
    __builtin_amdgcn_global_load_lds(                                       \
        (const __attribute__((address_space(1))) void*)s_,                  \
        (__attribute__((address_space(3))) void*)(smem + (R_) * 1024),      \
        16, 0, 0);                                                          \
} while (0)

#define ROWC(M_, IDX_) do {                                                 \
    float2 v_ = L[(IDX_)];                                                  \
    unsigned int mm_ = (M_);                                                \
    _Pragma("unroll")                                                       \
    for (int b = 0; b < 16; ++b) {                                          \
        float s_ = (mm_ & (1u << b)) ? 1.0f : 0.0f;                         \
        accx[b] = fmaf(s_, v_.x, accx[b]);                                  \
        accy[b] = fmaf(s_, v_.y, accy[b]);                                  \
    }                                                                       \
} while (0)

#define PAIR(R_, W_) do {                                                   \
    WAITV(W_);                                                              \
    ROWC((unsigned int)__builtin_amdgcn_readlane((int)vm, 2 * (R_)),        \
         (R_) * 128 + t);                                                   \
    ROWC((unsigned int)__builtin_amdgcn_readlane((int)vm, 2 * (R_) + 1),    \
         (R_) * 128 + 64 + t);                                              \
} while (0)

__global__ __launch_bounds__(64) void k3_stream(const float2* __restrict__ B2,
                                                const unsigned int* __restrict__ zmask,
                                                const int* __restrict__ inv,
                                                float* __restrict__ compact) {
    __shared__ alignas(16) char smem[16384];    // 32 rows x 64 float2
    float2* L = (float2*)smem;
    const int t  = threadIdx.x;                 // [0, 64)
    const int bx = blockIdx.x;                  // col window [0, 224)
    const int by = blockIdx.y;                  // n-chunk    [0, 64)
    const int n0   = by * 32;
    const int col2 = bx * 64 + t;               // [0, 14336)

    // Mask vector FIRST (so its auto-wait is vmcnt(16), not 0): lane l holds
    // zmask[n0 + (l&31)]; per-row masks later via readlane (no LDS, no bar).
    unsigned int vm = zmask[n0 + (t & 31)];

    const char*  gbase = (const char*)(B2 + (size_t)n0 * KN2 + bx * 64);
    const size_t SB    = (size_t)KN2 * sizeof(float2);   // row stride bytes

    float accx[16], accy[16];
    #pragma unroll
    for (int b = 0; b < 16; ++b) { accx[b] = 0.f; accy[b] = 0.f; }

    STAGE(0);  STAGE(1);  STAGE(2);  STAGE(3);
    STAGE(4);  STAGE(5);  STAGE(6);  STAGE(7);
    STAGE(8);  STAGE(9);  STAGE(10); STAGE(11);
    STAGE(12); STAGE(13); STAGE(14); STAGE(15);

    PAIR(0, 15);  PAIR(1, 14);  PAIR(2, 13);  PAIR(3, 12);
    PAIR(4, 11);  PAIR(5, 10);  PAIR(6, 9);   PAIR(7, 8);
    PAIR(8, 7);   PAIR(9, 6);   PAIR(10, 5);  PAIR(11, 4);
    PAIR(12, 3);  PAIR(13, 2);  PAIR(14, 1);  PAIR(15, 0);

    // Compact store: only columns that are some slot's representative.
    int r0 = inv[2 * col2];                      // even column
    int r1 = inv[2 * col2 + 1];                  // odd column
    float* cbase = compact + (size_t)by * 16 * 2048;
    if (r0 != INVNONE) {
        #pragma unroll
        for (int b = 0; b < 16; ++b) cbase[b * 2048 + r0] = accx[b];
    }
    if (r1 != INVNONE) {
        #pragma unroll
        for (int b = 0; b < 16; ++b) cbase[b * 2048 + r1] = accy[b];
    }
}

// ---------------------------------------------------------------------------
// k4: per output slot, sum NC chunk-partials of its representative column
// (fixed order). compact is 8 MB -> L2-hot.
__global__ __launch_bounds__(128) void k4_gather(const float* __restrict__ compact,
                                                 const int* __restrict__ ridx,
                                                 const int* __restrict__ inv,
                                                 float* __restrict__ out_z2) {
    int gid = blockIdx.x * 128 + threadIdx.x;   // [0, 32768)
    int b = gid >> 11, i = gid & (NN - 1);
    int rep = inv[ridx[i]];                     // always valid (ridx[i] needed)
    float acc = 0.f;
    #pragma unroll 8
    for (int c = 0; c < NC; ++c)                // independent loads, pipelined
        acc += compact[(size_t)(c * 16 + b) * 2048 + rep];
    out_z2[gid] = acc;
}

// ---------------------------------------------------------------------------
extern "C" void kernel_launch(void* const* d_in, const int* in_sizes, int n_in,
                              void* d_out, int out_size, void* d_ws, size_t ws_size,
                              hipStream_t stream) {
    const float* inputs    = (const float*)d_in[0];
    const float* old_v     = (const float*)d_in[1];
    const float* old_spike = (const float*)d_in[2];
    const float* W         = (const float*)d_in[3];
    const float* Bw        = (const float*)d_in[4];
    const int*   ridx      = (const int*)d_in[5];
    const int*   tt        = (const int*)d_in[6];
    float* out = (float*)d_out;

    // ws layout: [0,4MB) f64 partials | 64KB zmask | 128KB inv | 8MB compact
    char* ws = (char*)d_ws;
    double*       part    = (double*)ws;
    unsigned int* zmask   = (unsigned int*)(ws + (4u << 20));
    int*          inv     = (int*)(ws + (4u << 20) + (64u << 10));
    float*        compact = (float*)(ws + (4u << 20) + (192u << 10));

    k1_gemm <<<dim3(32, 16), 64, 0, stream>>>(inputs, W, part, zmask, inv);
    k2_point<<<128, 256, 0, stream>>>(part, old_v, old_spike, tt, ridx,
                                      out, zmask, inv);
    k3_stream<<<dim3(224, NC), 64, 0, stream>>>((const float2*)Bw, zmask,
                                                inv, compact);
    k4_gather<<<256, 128, 0, stream>>>(compact, ridx, inv, out + 65536);
}

// Round 13
// 91.850 us; speedup vs baseline: 5.1450x; 5.1450x over previous
//
#include <hip/hip_runtime.h>
#include <hip/hip_bf16.h>
#include <math.h>

// Problem constants
#define NB   16      // batch
#define NIN  512
#define NN   2048
#define KN   28672   // K*N

// ---------------------------------------------------------------------------
// k1: partial GEMM i_in = inputs @ W, f64 accumulation, deterministic order.
// part[ks][b][n], ks in [0,16) covering k = ks*32 .. ks*32+31.
// grid (32 n-chunks, 16 ks), block = 64 threads (one wave, 64 n's).
// ks==0 blocks also clear zmask (read only by k2/k3, after k1 completes).
__global__ __launch_bounds__(64) void k1_gemm(const float* __restrict__ inputs,
                                              const float* __restrict__ W,
                                              double* __restrict__ part,
                                              unsigned int* __restrict__ zmask) {
    const int n  = blockIdx.x * 64 + threadIdx.x;
    const int ks = blockIdx.y;
    if (ks == 0) zmask[n] = 0u;                 // fused clear
    const int k0 = ks * 32;
    double acc[16];
    #pragma unroll
    for (int b = 0; b < 16; ++b) acc[b] = 0.0;
    #pragma unroll 8
    for (int kk = 0; kk < 32; ++kk) {           // 8 W-loads batched in flight
        double w = (double)W[(size_t)(k0 + kk) * NN + n];   // coalesced 256B/wave
        #pragma unroll
        for (int b = 0; b < 16; ++b)                        // uniform scalar loads
            acc[b] += w * (double)inputs[b * NIN + k0 + kk];
    }
    #pragma unroll
    for (int b = 0; b < 16; ++b)
        part[(size_t)(ks * 16 + b) * NN + n] = acc[b];
}

// ---------------------------------------------------------------------------
// k2: deterministic reduce of 16 partials + LIF update. Writes new_z, new_v,
// and per-neuron 16-bit spike mask (atomicOr = order-independent).
__global__ __launch_bounds__(256) void k2_point(const double* __restrict__ part,
                                                const float* __restrict__ old_v,
                                                const float* __restrict__ old_spike,
                                                const int* __restrict__ tt_p,
                                                float* __restrict__ out,      // z @0, v @32768
                                                unsigned int* __restrict__ zmask) {
    int gid = blockIdx.x * 256 + threadIdx.x;   // [0, 32768)
    int b = gid >> 11, n = gid & (NN - 1);
    double s = 0.0;
    #pragma unroll
    for (int ks = 0; ks < 16; ++ks)             // fixed order -> deterministic
        s += part[(size_t)(ks * 16 + b) * NN + n];
    double tt   = (double)tt_p[0];
    double bias = 0.5 * sin(2.0 * 3.14159265358979323846 * 4.0 * (0.001 * tt));
    double d    = 0.9512294245007140;           // exp(-1/20)
    double i_in = s + bias;
    double nv   = d * (double)old_v[gid] + (1.0 - d) * i_in
                  - 0.03 * (double)old_spike[gid];
    bool z = nv > 0.03;                          // v_scaled > 0  <=>  nv > THR
    out[gid]           = z ? 1.0f : 0.0f;
    out[32768 + gid]   = (float)nv;
    if (z) atomicOr(&zmask[n], 1u << b);
}

// ---------------------------------------------------------------------------
// k3_gather: z2[b][i] = sum_n z[b][n] * B[n][ridx[i]] computed DIRECTLY on
// the ~2008 needed columns (16.4 MB of elements, ~211 MB line footprint ->
// L3-resident across replays) instead of streaming all 235 MB of B.
// One block per output slot i; r = ridx[i] is block-uniform. Wave w covers
// n in [w*512, w*512+512), lane t handles n = w*512 + it*64 + t (8 unrolled
// independent loads in flight). Deterministic shuffle-tree + LDS reduce.
__global__ __launch_bounds__(256) void k3_gather(const float* __restrict__ Bw,
                                                 const unsigned int* __restrict__ zmask,
                                                 const int* __restrict__ ridx,
                                                 float* __restrict__ out_z2) {
    __shared__ float psum[4][16];
    const int i = blockIdx.x;                   // output slot [0, 2048)
    const int r = ridx[i];                      // block-uniform column
    const int t = threadIdx.x & 63;
    const int w = threadIdx.x >> 6;

    float acc[16];
    #pragma unroll
    for (int b = 0; b < 16; ++b) acc[b] = 0.f;

    const int nbase = w * 512 + t;
    #pragma unroll
    for (int it = 0; it < 8; ++it) {            // 8 independent scattered loads
        int n = nbase + it * 64;
        float v = Bw[(size_t)n * KN + r];       // 1 line per lane (L3-served)
        unsigned int zm = zmask[n];             // coalesced, L2-hot
        #pragma unroll
        for (int b = 0; b < 16; ++b) {
            float s = (zm & (1u << b)) ? 1.0f : 0.0f;   // per-lane cndmask
            acc[b] = fmaf(s, v, acc[b]);
        }
    }

    // Intra-wave reduce: fixed butterfly order -> deterministic.
    #pragma unroll
    for (int b = 0; b < 16; ++b) {
        float x = acc[b];
        #pragma unroll
        for (int off = 32; off > 0; off >>= 1)
            x += __shfl_down(x, off, 64);
        acc[b] = x;                             // lane 0 holds wave sum
    }
    if (t == 0) {
        #pragma unroll
        for (int b = 0; b < 16; ++b) psum[w][b] = acc[b];
    }
    __syncthreads();
    if (threadIdx.x < 16) {
        int b = threadIdx.x;
        float s4 = ((psum[0][b] + psum[1][b]) + psum[2][b]) + psum[3][b];
        out_z2[b * NN + i] = s4;                // z2 flat [b][i]
    }
}

// ---------------------------------------------------------------------------
extern "C" void kernel_launch(void* const* d_in, const int* in_sizes, int n_in,
                              void* d_out, int out_size, void* d_ws, size_t ws_size,
                              hipStream_t stream) {
    const float* inputs    = (const float*)d_in[0];
    const float* old_v     = (const float*)d_in[1];
    const float* old_spike = (const float*)d_in[2];
    const float* W         = (const float*)d_in[3];
    const float* Bw        = (const float*)d_in[4];
    const int*   ridx      = (const int*)d_in[5];
    const int*   tt        = (const int*)d_in[6];
    float* out = (float*)d_out;

    // ws layout: [0,4MB) f64 partials | [4MB,+8KB) zmask
    char* ws = (char*)d_ws;
    double*       part  = (double*)ws;
    unsigned int* zmask = (unsigned int*)(ws + (4u << 20));

    k1_gemm  <<<dim3(32, 16), 64, 0, stream>>>(inputs, W, part, zmask);
    k2_point <<<128, 256, 0, stream>>>(part, old_v, old_spike, tt, out, zmask);
    k3_gather<<<2048, 256, 0, stream>>>(Bw, zmask, ridx, out + 65536);
}